// Round 1
// baseline (12.692 us; speedup 1.0000x reference)
//
#include <hip/hip_runtime.h>

// QualityPredictorLoss — the reference is identically 0.0 for ALL inputs:
//
//   order = argsort(-sims)          -> s = sims[order] is sorted DESCENDING,
//                                      so s[i] >= s[i+1] exactly for every i.
//   mask  = (g[:-1] < g[1:]) & (s[:-1] < s[1:])
//                                   -> second conjunct (s[i] < s[i+1]) is the
//                                      negation of the sort invariant: always
//                                      False (ties give ==, NaN compares give
//                                      False). mask is all-False.
//   loss  = sum(where(mask, ..., 0)) = 0.0  exactly.
//
// This holds for any q_emb/d_embs/c_emb/rates, so the correct (and optimal)
// kernel is O(1): write 0.0f to the scalar output. d_out is poisoned to 0xAA
// before timing, so we must store the zero unconditionally on every call.

__global__ void QualityPredictorLoss_89988154786576_kernel(float* out) {
    if (threadIdx.x == 0 && blockIdx.x == 0) {
        out[0] = 0.0f;
    }
}

extern "C" void kernel_launch(void* const* d_in, const int* in_sizes, int n_in,
                              void* d_out, int out_size, void* d_ws, size_t ws_size,
                              hipStream_t stream) {
    (void)d_in; (void)in_sizes; (void)n_in; (void)d_ws; (void)ws_size; (void)out_size;
    float* out = (float*)d_out;
    QualityPredictorLoss_89988154786576_kernel<<<1, 64, 0, stream>>>(out);
}